// Round 15
// baseline (172.616 us; speedup 1.0000x reference)
//
#include <hip/hip_runtime.h>

// RelationAwareDiscriminator:
//   out[b,u,v] = sigmoid( sum_{d,e} UE[u,d] * R[r[b],d,e] * VE[v,e] )
// Dedup: out[b] depends on b only via r[b] (64 distinct relations).
// R15: producer/consumer WAVE SPECIALIZATION. Every hybrid schedule caps at
// ~4 TB/s writes; the 6.7 TB/s movers have pure-memory wave streams. K2
// gives each block 4 producer waves (compute slabs into LDS ring) and 4
// consumer waves (ds_read -> 1KB NT stores only, fillBuffer-shaped).
// Sync = LDS flags + relaxed atomics + lgkmcnt(0) only (vmcnt never
// drained by sync). K1 = proven prep (T, VEt, match lists).

#define BATCH 512
#define DIM   128
#define NRELS 64
#define NTHR  256

typedef float floatx4 __attribute__((ext_vector_type(4)));

// ws layout (floats)
#define T_ELEMS   ((size_t)NRELS * DIM * BATCH)      // [rel][e][u]
#define VET_OFF   (T_ELEMS)                          // [e][v] 128x512
#define CNT_OFF   (T_ELEMS + (size_t)DIM * BATCH)    // 64 ints
#define LIST_OFF  (CNT_OFF + 64)                     // [rel][512] ints
#define WS_NEED   ((LIST_OFF + (size_t)NRELS * BATCH) * 4)

// ---------------- K1: T blocks (bid<512), match lists (512), VEt (513..520)
__global__ __launch_bounds__(NTHR, 2)
void rad_prep_kernel(const int* __restrict__ u_idx,
                     const int* __restrict__ v_idx,
                     const int* __restrict__ r_idx,
                     const float* __restrict__ nodes,   // [100000][128]
                     const float* __restrict__ rels,    // [64][128][128]
                     float* __restrict__ ws)
{
    const int bid = (int)blockIdx.x;
    const int t   = (int)threadIdx.x;

    if (bid == NRELS * 8) {
        __shared__ int s_cnt[NRELS];
        int* counts = (int*)(ws + CNT_OFF);
        int* lists  = (int*)(ws + LIST_OFF);
        if (t < NRELS) s_cnt[t] = 0;
        __syncthreads();
        for (int i = t; i < BATCH; i += NTHR) {
            const int rel = r_idx[i];
            const int pos = atomicAdd(&s_cnt[rel], 1);
            lists[rel * BATCH + pos] = i;
        }
        __syncthreads();
        if (t < NRELS) counts[t] = s_cnt[t];
        return;
    }
    if (bid > NRELS * 8) {
        const int v0 = (bid - NRELS * 8 - 1) * 64;
        float* VEt = ws + VET_OFF;
        for (int i = t; i < 64 * (DIM / 4); i += NTHR) {
            const int row = i & 63;
            const int dc  = i >> 6;
            const float4 val = *reinterpret_cast<const float4*>(
                nodes + (size_t)v_idx[v0 + row] * DIM + dc * 4);
            VEt[(dc * 4 + 0) * BATCH + v0 + row] = val.x;
            VEt[(dc * 4 + 1) * BATCH + v0 + row] = val.y;
            VEt[(dc * 4 + 2) * BATCH + v0 + row] = val.z;
            VEt[(dc * 4 + 3) * BATCH + v0 + row] = val.w;
        }
        return;
    }

    // ---- T block: T[rel][e][u] = sum_d UE[u,d] * R[rel][d,e]
    const int rel = bid >> 3;
    const int ut0 = (bid & 7) * 64;

    __shared__ __align__(16) float UEsT[DIM * 64];  // [d][u] 32 KB
    __shared__ __align__(16) float Rs[16 * DIM];    // [dd][e] 8 KB

    const int tu = t >> 4;
    const int tx = t & 15;

    for (int i = t; i < 64 * (DIM / 4); i += NTHR) {
        const int row = i & 63;
        const int dc  = i >> 6;
        const float4 val = *reinterpret_cast<const float4*>(
            nodes + (size_t)u_idx[ut0 + row] * DIM + dc * 4);
        UEsT[(dc * 4 + 0) * 64 + row] = val.x;
        UEsT[(dc * 4 + 1) * 64 + row] = val.y;
        UEsT[(dc * 4 + 2) * 64 + row] = val.z;
        UEsT[(dc * 4 + 3) * 64 + row] = val.w;
    }

    float accA[4][8];
    #pragma unroll
    for (int i = 0; i < 4; ++i)
        #pragma unroll
        for (int j = 0; j < 8; ++j) accA[i][j] = 0.f;

    const float* Rbase = rels + (size_t)rel * DIM * DIM;
    for (int dch = 0; dch < DIM / 16; ++dch) {
        __syncthreads();
        for (int i = t; i < 16 * (DIM / 4); i += NTHR) {
            const int rr = i >> 5;
            const int cc = i & 31;
            *reinterpret_cast<float4*>(Rs + rr * DIM + cc * 4) =
                *reinterpret_cast<const float4*>(
                    Rbase + (size_t)(dch * 16 + rr) * DIM + cc * 4);
        }
        __syncthreads();
        #pragma unroll
        for (int dd = 0; dd < 16; ++dd) {
            const int d = dch * 16 + dd;
            const float4 a  = *reinterpret_cast<const float4*>(UEsT + d * 64 + tu * 4);
            const float4 b0 = *reinterpret_cast<const float4*>(Rs + dd * DIM + tx * 4);
            const float4 b1 = *reinterpret_cast<const float4*>(Rs + dd * DIM + 64 + tx * 4);
            const float av[4] = {a.x, a.y, a.z, a.w};
            const float bv[8] = {b0.x, b0.y, b0.z, b0.w, b1.x, b1.y, b1.z, b1.w};
            #pragma unroll
            for (int i = 0; i < 4; ++i)
                #pragma unroll
                for (int j = 0; j < 8; ++j)
                    accA[i][j] = fmaf(av[i], bv[j], accA[i][j]);
        }
    }

    #pragma unroll
    for (int j = 0; j < 8; ++j) {
        const int e = (j < 4) ? (tx * 4 + j) : (64 + tx * 4 + (j - 4));
        float4 w4 = make_float4(accA[0][j], accA[1][j], accA[2][j], accA[3][j]);
        *reinterpret_cast<float4*>(
            ws + ((size_t)rel * DIM + e) * BATCH + ut0 + tu * 4) = w4;
    }
}

// ---------------- K2: wave-specialized producer/consumer
__global__ __launch_bounds__(512, 2)
void rad_ps_kernel(const float* __restrict__ ws,
                   float* __restrict__ out)       // [512][512][512]
{
    // XCD-colocating swizzle (R7 scheme): 8 ut-siblings of a rel share an
    // XCD -> T[rel] slice + VEt served from that XCD's L2.
    const int bid = (int)blockIdx.x;
    const int rel = ((bid & 7) << 3) | (bid >> 6);
    const int ut0 = ((bid >> 3) & 7) * 64;

    __shared__ int s_match[BATCH];
    __shared__ __align__(16) float TsT[DIM * 64];    // [e][u] 32 KB
    __shared__ __align__(16) float S[4][8 * BATCH];  // 4 bufs x 16 KB
    __shared__ int produced[8];
    __shared__ int consumed[8];

    const int t = (int)threadIdx.x;
    const int w = t >> 6;     // wave 0..7
    const int l = t & 63;

    const int* counts = (const int*)(ws + CNT_OFF);
    const int* lists  = (const int*)(ws + LIST_OFF) + rel * BATCH;
    const int  mc     = counts[rel];
    if (mc == 0) return;      // uniform: all threads exit together

    if (t < 8) { produced[t] = 0; consumed[t] = 0; }
    for (int i = t; i < mc; i += 512) s_match[i] = lists[i];
    // Load T slice [e][ut0..+63] -> TsT[e][u] (both sides coalesced).
    const float* Tbase = ws + (size_t)rel * DIM * BATCH + ut0;
    for (int i = t; i < DIM * 16; i += 512) {
        const int e  = i >> 4;
        const int uc = i & 15;
        *reinterpret_cast<float4*>(TsT + e * 64 + uc * 4) =
            *reinterpret_cast<const float4*>(Tbase + (size_t)e * BATCH + uc * 4);
    }
    __syncthreads();   // the ONLY all-wave barrier

    if (w < 4) {
        // ---------- PRODUCER wave w: slabs s = w and w+4 (rows s*8..+7)
        const float* vb = ws + VET_OFF;
        for (int half = 0; half < 2; ++half) {
            const int s  = w + half * 4;
            const int r0 = s * 8;
            if (half == 1) {
                // buffer w reused: wait until slab w fully consumed
                while (__hip_atomic_load(&consumed[w], __ATOMIC_RELAXED,
                                         __HIP_MEMORY_SCOPE_WORKGROUP) < 4)
                    __builtin_amdgcn_s_sleep(1);
            }
            float acc[8][8];
            #pragma unroll
            for (int r = 0; r < 8; ++r)
                #pragma unroll
                for (int c = 0; c < 8; ++c) acc[r][c] = 0.f;

            // No barriers in this loop: LDS broadcasts + L2 streaming loads.
            #pragma unroll 2
            for (int e = 0; e < DIM; ++e) {
                const float4 t0 = *reinterpret_cast<const float4*>(TsT + e * 64 + r0);
                const float4 t1 = *reinterpret_cast<const float4*>(TsT + e * 64 + r0 + 4);
                const float4 b0 = *reinterpret_cast<const float4*>(
                    vb + (size_t)e * BATCH + l * 4);
                const float4 b1 = *reinterpret_cast<const float4*>(
                    vb + (size_t)e * BATCH + 256 + l * 4);
                const float tr[8] = {t0.x, t0.y, t0.z, t0.w, t1.x, t1.y, t1.z, t1.w};
                const float c0[4] = {b0.x, b0.y, b0.z, b0.w};
                const float c1[4] = {b1.x, b1.y, b1.z, b1.w};
                #pragma unroll
                for (int r = 0; r < 8; ++r) {
                    #pragma unroll
                    for (int c = 0; c < 4; ++c) {
                        acc[r][c]     = fmaf(tr[r], c0[c], acc[r][c]);
                        acc[r][c + 4] = fmaf(tr[r], c1[c], acc[r][c + 4]);
                    }
                }
            }
            // sigmoid + slab write: S[w][r][l*4..] and [256+l*4..]
            float* Sb = S[w];
            #pragma unroll
            for (int r = 0; r < 8; ++r) {
                float4 g0, g1;
                g0.x = 1.f / (1.f + __expf(-acc[r][0]));
                g0.y = 1.f / (1.f + __expf(-acc[r][1]));
                g0.z = 1.f / (1.f + __expf(-acc[r][2]));
                g0.w = 1.f / (1.f + __expf(-acc[r][3]));
                g1.x = 1.f / (1.f + __expf(-acc[r][4]));
                g1.y = 1.f / (1.f + __expf(-acc[r][5]));
                g1.z = 1.f / (1.f + __expf(-acc[r][6]));
                g1.w = 1.f / (1.f + __expf(-acc[r][7]));
                *reinterpret_cast<float4*>(Sb + r * BATCH + l * 4) = g0;
                *reinterpret_cast<float4*>(Sb + r * BATCH + 256 + l * 4) = g1;
            }
            // slab visible before flag: drain LDS writes, then relaxed flag
            asm volatile("s_waitcnt lgkmcnt(0)" ::: "memory");
            __hip_atomic_store(&produced[s], 1, __ATOMIC_RELAXED,
                               __HIP_MEMORY_SCOPE_WORKGROUP);
        }
    } else {
        // ---------- CONSUMER wave k: pure ds_read -> NT store stream
        const int k = w - 4;
        for (int s = 0; s < 8; ++s) {
            while (!__hip_atomic_load(&produced[s], __ATOMIC_RELAXED,
                                      __HIP_MEMORY_SCOPE_WORKGROUP))
                __builtin_amdgcn_s_sleep(1);
            const float* Sb = S[s & 3];
            const size_t rowbase = (size_t)(ut0 + s * 8) << 9;
            for (int m = k; m < mc; m += 4) {
                const int bb = s_match[m];
                float* ob = out + ((size_t)bb << 18) + rowbase + l * 4;
                #pragma unroll
                for (int r = 0; r < 8; ++r) {
                    const floatx4 v0 = *reinterpret_cast<const floatx4*>(
                        Sb + r * BATCH + l * 4);
                    const floatx4 v1 = *reinterpret_cast<const floatx4*>(
                        Sb + r * BATCH + 256 + l * 4);
                    __builtin_nontemporal_store(
                        v0, reinterpret_cast<floatx4*>(ob + ((size_t)r << 9)));
                    __builtin_nontemporal_store(
                        v1, reinterpret_cast<floatx4*>(ob + ((size_t)r << 9) + 256));
                }
            }
            // LDS reads of this slab are complete (stores consumed them after
            // lgkmcnt waits); signal buffer free. vmcnt NOT drained.
            asm volatile("s_waitcnt lgkmcnt(0)" ::: "memory");
            __hip_atomic_fetch_add(&consumed[s], 1, __ATOMIC_RELAXED,
                                   __HIP_MEMORY_SCOPE_WORKGROUP);
        }
    }
}

// ---------------- Fallback: proven R7 fused kernel (142.7 us) if ws too small
__device__ __forceinline__ void lds_barrier() {
    asm volatile("s_waitcnt lgkmcnt(0)" ::: "memory");
    __builtin_amdgcn_s_barrier();
    __builtin_amdgcn_sched_barrier(0);
}

__global__ __launch_bounds__(NTHR, 2)
void rad_fused_kernel(const int* __restrict__ u_idx,
                      const int* __restrict__ v_idx,
                      const int* __restrict__ r_idx,
                      const float* __restrict__ nodes,
                      const float* __restrict__ rels,
                      float* __restrict__ out)
{
    const int bid = (int)blockIdx.x;
    const int rel = ((bid & 7) << 3) | (bid >> 6);
    const int ut0 = ((bid >> 3) & 7) * 64;

    __shared__ int s_match[BATCH];
    __shared__ int s_mc;
    __shared__ __align__(16) float s_TsT[DIM * 64];
    __shared__ __align__(16) float s_buf[DIM * 64 + 16 * DIM];

    const int t  = (int)threadIdx.x;
    const int tu = t >> 4;
    const int tx = t & 15;

    if (t == 0) s_mc = 0;
    __syncthreads();
    for (int i = t; i < BATCH; i += NTHR) {
        if (r_idx[i] == rel) {
            int p = atomicAdd(&s_mc, 1);
            s_match[p] = i;
        }
    }

    float* UEsT = s_buf;
    float* Rs   = s_buf + DIM * 64;

    for (int i = t; i < 64 * (DIM / 4); i += NTHR) {
        const int row = i & 63;
        const int dc  = i >> 6;
        const float4 val = *reinterpret_cast<const float4*>(
            nodes + (size_t)u_idx[ut0 + row] * DIM + dc * 4);
        UEsT[(dc * 4 + 0) * 64 + row] = val.x;
        UEsT[(dc * 4 + 1) * 64 + row] = val.y;
        UEsT[(dc * 4 + 2) * 64 + row] = val.z;
        UEsT[(dc * 4 + 3) * 64 + row] = val.w;
    }
    __syncthreads();
    const int mc = s_mc;
    if (mc == 0) return;

    float accA[4][8];
    #pragma unroll
    for (int i = 0; i < 4; ++i)
        #pragma unroll
        for (int j = 0; j < 8; ++j) accA[i][j] = 0.f;

    const float* Rbase = rels + (size_t)rel * DIM * DIM;
    for (int dch = 0; dch < DIM / 16; ++dch) {
        for (int i = t; i < 16 * (DIM / 4); i += NTHR) {
            const int rr = i >> 5;
            const int cc = i & 31;
            *reinterpret_cast<float4*>(Rs + rr * DIM + cc * 4) =
                *reinterpret_cast<const float4*>(
                    Rbase + (size_t)(dch * 16 + rr) * DIM + cc * 4);
        }
        lds_barrier();
        #pragma unroll
        for (int dd = 0; dd < 16; ++dd) {
            const int d = dch * 16 + dd;
            const float4 a  = *reinterpret_cast<const float4*>(UEsT + d * 64 + tu * 4);
            const float4 b0 = *reinterpret_cast<const float4*>(Rs + dd * DIM + tx * 4);
            const float4 b1 = *reinterpret_cast<const float4*>(Rs + dd * DIM + 64 + tx * 4);
            const float av[4] = {a.x, a.y, a.z, a.w};
            const float bv[8] = {b0.x, b0.y, b0.z, b0.w, b1.x, b1.y, b1.z, b1.w};
            #pragma unroll
            for (int i = 0; i < 4; ++i)
                #pragma unroll
                for (int j = 0; j < 8; ++j)
                    accA[i][j] = fmaf(av[i], bv[j], accA[i][j]);
        }
        lds_barrier();
    }

    #pragma unroll
    for (int j = 0; j < 8; ++j) {
        const int e = (j < 4) ? (tx * 4 + j) : (64 + tx * 4 + (j - 4));
        #pragma unroll
        for (int i = 0; i < 4; ++i)
            s_TsT[e * 64 + tu * 4 + i] = accA[i][j];
    }

    float* VEsT = s_buf;
    for (int vt = 0; vt < BATCH / 64; ++vt) {
        lds_barrier();
        for (int i = t; i < 64 * (DIM / 4); i += NTHR) {
            const int row = i & 63;
            const int ec  = i >> 6;
            const float4 val = *reinterpret_cast<const float4*>(
                nodes + (size_t)v_idx[vt * 64 + row] * DIM + ec * 4);
            VEsT[(ec * 4 + 0) * 64 + row] = val.x;
            VEsT[(ec * 4 + 1) * 64 + row] = val.y;
            VEsT[(ec * 4 + 2) * 64 + row] = val.z;
            VEsT[(ec * 4 + 3) * 64 + row] = val.w;
        }
        lds_barrier();

        float acc[4][4];
        #pragma unroll
        for (int i = 0; i < 4; ++i)
            #pragma unroll
            for (int j = 0; j < 4; ++j) acc[i][j] = 0.f;

        #pragma unroll 8
        for (int e = 0; e < DIM; ++e) {
            const float4 a = *reinterpret_cast<const float4*>(s_TsT + e * 64 + tu * 4);
            const float4 b = *reinterpret_cast<const float4*>(VEsT  + e * 64 + tx * 4);
            const float av[4] = {a.x, a.y, a.z, a.w};
            const float bv[4] = {b.x, b.y, b.z, b.w};
            #pragma unroll
            for (int i = 0; i < 4; ++i)
                #pragma unroll
                for (int j = 0; j < 4; ++j)
                    acc[i][j] = fmaf(av[i], bv[j], acc[i][j]);
        }

        floatx4 sg[4];
        #pragma unroll
        for (int i = 0; i < 4; ++i) {
            sg[i].x = 1.f / (1.f + __expf(-acc[i][0]));
            sg[i].y = 1.f / (1.f + __expf(-acc[i][1]));
            sg[i].z = 1.f / (1.f + __expf(-acc[i][2]));
            sg[i].w = 1.f / (1.f + __expf(-acc[i][3]));
        }

        for (int m = 0; m < mc; ++m) {
            const int bb = s_match[m];
            float* obase = out + (size_t)bb * BATCH * BATCH + vt * 64 + tx * 4;
            #pragma unroll
            for (int i = 0; i < 4; ++i) {
                __builtin_nontemporal_store(
                    sg[i], reinterpret_cast<floatx4*>(
                               obase + (size_t)(ut0 + tu * 4 + i) * BATCH));
            }
        }
    }
}

extern "C" void kernel_launch(void* const* d_in, const int* in_sizes, int n_in,
                              void* d_out, int out_size, void* d_ws, size_t ws_size,
                              hipStream_t stream) {
    const int*   u_idx = (const int*)d_in[0];
    const int*   v_idx = (const int*)d_in[1];
    const int*   r_idx = (const int*)d_in[2];
    const float* nodes = (const float*)d_in[3];
    const float* rels  = (const float*)d_in[4];
    float* out = (float*)d_out;

    if (ws_size >= WS_NEED) {
        float* ws = (float*)d_ws;
        rad_prep_kernel<<<dim3(NRELS * 8 + 1 + 8), dim3(NTHR), 0, stream>>>(
            u_idx, v_idx, r_idx, nodes, rels, ws);
        rad_ps_kernel<<<dim3(NRELS * 8), dim3(512), 0, stream>>>(ws, out);
    } else {
        rad_fused_kernel<<<dim3(NRELS * 8), dim3(NTHR), 0, stream>>>(
            u_idx, v_idx, r_idx, nodes, rels, out);
    }
}